// Round 8
// baseline (290.500 us; speedup 1.0000x reference)
//
#include <hip/hip_runtime.h>
#include <hip/hip_bf16.h>
#include <hip/hip_fp8.h>
#include <math.h>

#define N_NODES 50000
#define N_EDGES 800000
#define NFEAT 3
#define C1 512
#define C2 256
#define C3 128
#define NGRAPH 100
#define NCLS 2
#define PSPLIT 8
#define NEBLK 3125      // ceil(N_EDGES / 256) -- 1 edge per thread, max TLP for atomics
#define WBLK 640        // (C1*C2 + C2*C3) / 256

typedef short bh8 __attribute__((ext_vector_type(8)));   // 8 bf16 bit-patterns (4 VGPRs)
typedef float f32x4 __attribute__((ext_vector_type(4))); // MFMA accumulator

__device__ __forceinline__ short f2bf(float x) {
    __hip_bfloat16 h = __float2bfloat16(x);
    return *reinterpret_cast<short*>(&h);
}
__device__ __forceinline__ float bflo(unsigned int u) { return __uint_as_float(u << 16); }
__device__ __forceinline__ float bfhi(unsigned int u) { return __uint_as_float(u & 0xffff0000u); }
__device__ __forceinline__ unsigned int packbf(float a, float b) {
    return (unsigned int)(unsigned short)f2bf(a) | ((unsigned int)(unsigned short)f2bf(b) << 16);
}
// OCP e4m3 fp8 encode; packed-pair decode (HW v_cvt_pk_f32_fp8 on gfx950)
__device__ __forceinline__ unsigned char f2fp8(float x) {
    __hip_fp8_e4m3 q(x);
    return (unsigned char)q.__x;
}
__device__ __forceinline__ float2 fp8x2(unsigned short u) {
    __hip_fp8x2_e4m3 q; q.__x = u; return (float2)q;
}

// async global->LDS, 16B per lane (global_load_lds_dwordx4). LDS dest must be
// wave-uniform base + lane*16 (HW constraint, m104); global src is per-lane.
__device__ __forceinline__ void gload16(const void* g, void* l) {
    __builtin_amdgcn_global_load_lds((const __attribute__((address_space(1))) void*)g,
                                     (__attribute__((address_space(3))) void*)l, 16, 0, 0);
}

// ---- degree count (single-pass, 1 edge/thread for max TLP) + weight prep fused ----
// Atomic-heavy kernels are LATENCY machines: round-6's 4-atomics/thread 782-block
// form ran at 27% occupancy and ~46us; 1 atomic/thread x 12.5K waves hides the
// ~700cy coherence-point RTT. Contention is per-address (16/addr here): negligible.

__global__ void count_prep(const int* __restrict__ col, int* __restrict__ counts,
                           const float* __restrict__ W2, const float* __restrict__ W3,
                           short* __restrict__ W2t, short* __restrict__ W3t) {
    int b = blockIdx.x;
    if (b < NEBLK) {
        int e = b * 256 + threadIdx.x;
        if (e < N_EDGES) atomicAdd(&counts[col[e]], 1);
    } else {
        int idx = (b - NEBLK) * 256 + threadIdx.x;
        if (idx < C1 * C2) {
            int n = idx / C1, k = idx % C1;
            W2t[idx] = f2bf(W2[k * C2 + n]);
        } else if (idx < C1 * C2 + C2 * C3) {
            int j = idx - C1 * C2;
            int n = j / C2, k = j % C2;
            W3t[j] = f2bf(W3[k * C3 + n]);
        }
    }
}

// ------- CSR build: per-chunk scan (fused dis + packed xd={x,dis}) -------

__global__ void scan_chunks(const int* __restrict__ counts, const float* __restrict__ x,
                            int* __restrict__ offsets, int* __restrict__ chunksums,
                            float* __restrict__ dis, float4* __restrict__ xd) {
    __shared__ int s[256];
    int b = blockIdx.x, t = threadIdx.x;
    int i = b * 256 + t;
    int v = (i < N_NODES) ? counts[i] : 0;
    if (i < N_NODES) {
        float d = rsqrtf((float)(v + 1)); // +1 self loop
        dis[i] = d;
        xd[i] = make_float4(x[i * 3 + 0], x[i * 3 + 1], x[i * 3 + 2], d);
    }
    s[t] = v;
    __syncthreads();
    for (int d = 1; d < 256; d <<= 1) {
        int add = (t >= d) ? s[t - d] : 0;
        __syncthreads();
        s[t] += add;
        __syncthreads();
    }
    if (i < N_NODES) offsets[i + 1] = s[t];
    if (t == 255) chunksums[b] = s[255];
}

// finalize offsets: every block redundantly scans the 196 raw chunk sums in LDS,
// then applies its chunk offset. Also initializes cursor[] = final offsets.

__global__ void finalize_offsets(int* __restrict__ offsets, const int* __restrict__ chunksums,
                                 int* __restrict__ cursor) {
    __shared__ int s[256];
    int b = blockIdx.x, t = threadIdx.x;
    int nck = (N_NODES + 255) / 256; // 196
    s[t] = (t < nck) ? chunksums[t] : 0;
    __syncthreads();
    for (int d = 1; d < 256; d <<= 1) {
        int add = (t >= d) ? s[t - d] : 0;
        __syncthreads();
        s[t] += add;
        __syncthreads();
    }
    int add = (b == 0) ? 0 : s[b - 1];
    int i = b * 256 + t;
    if (i < N_NODES) {
        int val = offsets[i + 1] + add;
        offsets[i + 1] = val;
        if (i + 1 < N_NODES) cursor[i + 1] = val;
    }
    if (i == 0) { offsets[0] = 0; cursor[0] = 0; }
}

// single-pass CSR scatter, 1 edge/thread (TLP hides the atomic->store chain).
// csr_src order within a node's list is atomic grab order -- sums are order-insensitive.

__global__ void scatter_edges(const int* __restrict__ rowi, const int* __restrict__ coli,
                              int* __restrict__ cursor, int* __restrict__ csr_src) {
    int e = blockIdx.x * 256 + threadIdx.x;
    if (e < N_EDGES) {
        int p = atomicAdd(&cursor[coli[e]], 1);
        csr_src[p] = rowi[e];
    }
}

// ---- FUSED feat-aggregate + layer1 + GEMM2: m2 = (di*relu(agg(x)@W1+b1)) @ W2t^T, fp8 out ----
// Prologue computes the block's 128 aggx rows in-LDS (16 lanes/node, shuffle-reduced).
// Bs staging uses global_load_lds width=16 (lane-linear LDS dest, per-lane global src).

__global__ __launch_bounds__(512, 4) void gemm_l1(const float4* __restrict__ xd,
                                                  const int* __restrict__ offsets,
                                                  const int* __restrict__ csr_src,
                                                  const float* __restrict__ W1,
                                                  const float* __restrict__ b1,
                                                  const short* __restrict__ Bt,
                                                  unsigned char* __restrict__ Cmat, int M) {
    __shared__ short As[128 * 32];
    __shared__ short Bs[C2 * 32];
    __shared__ float sW1[3 * C1];
    __shared__ float sb1[C1];
    __shared__ float sa[128 * 3];
    __shared__ float sd[128];
    int bm = blockIdx.x * 128;
    int t = threadIdx.x;
    int wave = t >> 6, lane = t & 63, quad = lane >> 4, l16 = lane & 15;
    int wm = (wave >> 2) * 64;
    int wn = (wave & 3) * 64;
    f32x4 acc[4][4] = {};

    for (int j = t; j < 3 * C1; j += 512) sW1[j] = W1[j];
    if (t < C1) sb1[t] = b1[t];

    // prologue: 4 rounds x 32 concurrent nodes (16 lanes each) -> sa, sd
    int lg = t & 15;
#pragma unroll
    for (int rnd = 0; rnd < 4; ++rnd) {
        int rloc = rnd * 32 + (t >> 4);         // 0..127
        int i = bm + rloc; if (i > M - 1) i = M - 1;
        int s0 = offsets[i], e0 = offsets[i + 1];
        float a0 = 0.f, a1 = 0.f, a2 = 0.f;
        for (int p = s0 + lg; p < e0; p += 16) {
            int r = csr_src[p];
            float4 v = xd[r];
            a0 += v.w * v.x;
            a1 += v.w * v.y;
            a2 += v.w * v.z;
        }
#pragma unroll
        for (int m = 1; m < 16; m <<= 1) {
            a0 += __shfl_xor(a0, m);
            a1 += __shfl_xor(a1, m);
            a2 += __shfl_xor(a2, m);
        }
        if (lg == 0) {
            float4 self = xd[i];
            float di = self.w;
            a0 += di * self.x; a1 += di * self.y; a2 += di * self.z;
            sa[rloc * 3 + 0] = di * a0;
            sa[rloc * 3 + 1] = di * a1;
            sa[rloc * 3 + 2] = di * a2;
            sd[rloc] = di;
        }
    }
    __syncthreads();

    int ar = t >> 2, ak = (t & 3) * 8;
    float a0 = sa[ar * 3 + 0], a1 = sa[ar * 3 + 1], a2 = sa[ar * 3 + 2];
    float drow = sd[ar];

    // staging chunk ids for Bs (two per thread): c -> row c>>2, koff (c&3)*8
    int c0 = t, c1 = 512 + t;
    int b0row = c0 >> 2, b0off = (c0 & 3) * 8;
    int b1row = c1 >> 2, b1off = (c1 & 3) * 8;

    for (int k0 = 0; k0 < C1; k0 += 32) {
#pragma unroll
        for (int j = 0; j < 8; ++j) {
            int k = k0 + ak + j;
            float v = a0 * sW1[k] + a1 * sW1[C1 + k] + a2 * sW1[2 * C1 + k] + sb1[k];
            As[ar * 32 + ak + j] = f2bf(drow * fmaxf(v, 0.f));
        }
        gload16(Bt + (size_t)b0row * C1 + k0 + b0off, &Bs[c0 * 8]);
        gload16(Bt + (size_t)b1row * C1 + k0 + b1off, &Bs[c1 * 8]);
        __syncthreads();
        bh8 af[4], bf[4];
#pragma unroll
        for (int mt = 0; mt < 4; ++mt)
            af[mt] = *(const bh8*)&As[(wm + mt * 16 + l16) * 32 + quad * 8];
#pragma unroll
        for (int nt = 0; nt < 4; ++nt)
            bf[nt] = *(const bh8*)&Bs[(wn + nt * 16 + l16) * 32 + quad * 8];
#pragma unroll
        for (int mt = 0; mt < 4; ++mt)
#pragma unroll
            for (int nt = 0; nt < 4; ++nt)
                acc[mt][nt] = __builtin_amdgcn_mfma_f32_16x16x32_bf16(af[mt], bf[nt], acc[mt][nt], 0, 0, 0);
        __syncthreads();
    }

#pragma unroll
    for (int mt = 0; mt < 4; ++mt)
#pragma unroll
        for (int nt = 0; nt < 4; ++nt) {
            int colc = wn + nt * 16 + l16;
#pragma unroll
            for (int r = 0; r < 4; ++r) {
                int rowc = bm + wm + mt * 16 + quad * 4 + r;
                if (rowc < M) Cmat[(size_t)rowc * C2 + colc] = f2fp8(acc[mt][nt][r]);
            }
        }
}

// ------- bf16 MFMA GEMM (K=256, BN=128), OUTPUT FP8: C[M x BN] = A[M x K] * Bt^T -------
// A and B staging via global_load_lds width=16 (lane-linear LDS byte 16t).

template <int K, int BN>
__global__ __launch_bounds__(512, 4) void gemm_bf16(const short* __restrict__ A,
                                                    const short* __restrict__ Bt,
                                                    unsigned char* __restrict__ Cmat, int M) {
    __shared__ short As[128 * 32];
    __shared__ short Bs[BN * 32];
    constexpr int NT = BN / 64;
    int bm = blockIdx.x * 128;
    int t = threadIdx.x;
    int wave = t >> 6, lane = t & 63, quad = lane >> 4, l16 = lane & 15;
    int wm = (wave >> 2) * 64;
    int wn = (wave & 3) * (BN / 4);
    f32x4 acc[4][NT] = {};

    int ar = t >> 2, ak = (t & 3) * 8;
    int agr = bm + ar; if (agr > M - 1) agr = M - 1;
    const short* aptr = A + (size_t)agr * K + ak;
    const short* bptr = Bt + (size_t)(t >> 2) * K + ((t & 3) * 8); // BN==128 layout

    for (int k0 = 0; k0 < K; k0 += 32) {
        gload16(aptr + k0, &As[t * 8]);
        static_assert(BN == 128, "staging specialized for BN==128");
        gload16(bptr + k0, &Bs[t * 8]);
        __syncthreads();
        bh8 af[4], bf[NT];
#pragma unroll
        for (int mt = 0; mt < 4; ++mt)
            af[mt] = *(const bh8*)&As[(wm + mt * 16 + l16) * 32 + quad * 8];
#pragma unroll
        for (int nt = 0; nt < NT; ++nt)
            bf[nt] = *(const bh8*)&Bs[(wn + nt * 16 + l16) * 32 + quad * 8];
#pragma unroll
        for (int mt = 0; mt < 4; ++mt)
#pragma unroll
            for (int nt = 0; nt < NT; ++nt)
                acc[mt][nt] = __builtin_amdgcn_mfma_f32_16x16x32_bf16(af[mt], bf[nt], acc[mt][nt], 0, 0, 0);
        __syncthreads();
    }

#pragma unroll
    for (int mt = 0; mt < 4; ++mt)
#pragma unroll
        for (int nt = 0; nt < NT; ++nt) {
            int colc = wn + nt * 16 + l16;
#pragma unroll
            for (int r = 0; r < 4; ++r) {
                int rowc = bm + wm + mt * 16 + quad * 4 + r;
                if (rowc < M) Cmat[(size_t)rowc * BN + colc] = f2fp8(acc[mt][nt][r]);
            }
        }
}

// ---- fp8-message aggregation, wave-per-node, 16-deep masked gather batches ----

template <int C, bool PRESCALE>
__global__ __launch_bounds__(256) void aggregate_w(const unsigned char* __restrict__ m,
                                                   const int* __restrict__ offsets,
                                                   const int* __restrict__ csr_src,
                                                   const float* __restrict__ dis,
                                                   const float* __restrict__ bias,
                                                   short* __restrict__ out) {
    int i = blockIdx.x * 4 + (threadIdx.x >> 6);
    if (i >= N_NODES) return;
    int lane = threadIdx.x & 63;
    int s = __builtin_amdgcn_readfirstlane(offsets[i]);
    int e = __builtin_amdgcn_readfirstlane(offsets[i + 1]);
    float di = __uint_as_float(__builtin_amdgcn_readfirstlane(__float_as_uint(dis[i])));

    if constexpr (C == 256) {
        // lane owns channels 4*lane .. 4*lane+3 (one uint = 4 fp8)
        const unsigned int* mu = (const unsigned int*)m;
        unsigned int su = mu[(size_t)i * (C / 4) + lane];
        float2 slo = fp8x2((unsigned short)(su & 0xffffu));
        float2 shi = fp8x2((unsigned short)(su >> 16));
        float a0 = slo.x, a1 = slo.y, a2 = shi.x, a3 = shi.y;
        int p = s;
        for (; p + 16 <= e; p += 16) {
            unsigned int u[16];
#pragma unroll
            for (int j = 0; j < 16; ++j) {
                int r = csr_src[p + j];
                u[j] = mu[(size_t)r * (C / 4) + lane];
            }
#pragma unroll
            for (int j = 0; j < 16; ++j) {
                float2 lo = fp8x2((unsigned short)(u[j] & 0xffffu));
                float2 hi = fp8x2((unsigned short)(u[j] >> 16));
                a0 += lo.x; a1 += lo.y; a2 += hi.x; a3 += hi.y;
            }
        }
        if (p < e) {
            unsigned int u[16];
            float sc[16];
#pragma unroll
            for (int j = 0; j < 16; ++j) {
                int q = p + j;
                sc[j] = (q < e) ? 1.f : 0.f;
                int r = csr_src[(q < e) ? q : e - 1];
                u[j] = mu[(size_t)r * (C / 4) + lane];
            }
#pragma unroll
            for (int j = 0; j < 16; ++j) {
                float2 lo = fp8x2((unsigned short)(u[j] & 0xffffu));
                float2 hi = fp8x2((unsigned short)(u[j] >> 16));
                a0 = fmaf(sc[j], lo.x, a0);
                a1 = fmaf(sc[j], lo.y, a1);
                a2 = fmaf(sc[j], hi.x, a2);
                a3 = fmaf(sc[j], hi.y, a3);
            }
        }
        float4 b = *(const float4*)&bias[4 * lane];
        a0 = fmaxf(di * a0 + b.x, 0.f);
        a1 = fmaxf(di * a1 + b.y, 0.f);
        a2 = fmaxf(di * a2 + b.z, 0.f);
        a3 = fmaxf(di * a3 + b.w, 0.f);
        if (PRESCALE) { a0 *= di; a1 *= di; a2 *= di; a3 *= di; }
        uint2 o;
        o.x = packbf(a0, a1);
        o.y = packbf(a2, a3);
        *(uint2*)(out + (size_t)i * C + 4 * lane) = o;
    } else {
        // C == 128: lane owns channels 2*lane, 2*lane+1 (one ushort = 2 fp8)
        const unsigned short* mu = (const unsigned short*)m;
        float2 sf = fp8x2(mu[(size_t)i * (C / 2) + lane]);
        float a0 = sf.x, a1 = sf.y;
        int p = s;
        for (; p + 16 <= e; p += 16) {
            unsigned short u[16];
#pragma unroll
            for (int j = 0; j < 16; ++j) {
                int r = csr_src[p + j];
                u[j] = mu[(size_t)r * (C / 2) + lane];
            }
#pragma unroll
            for (int j = 0; j < 16; ++j) {
                float2 f = fp8x2(u[j]);
                a0 += f.x; a1 += f.y;
            }
        }
        if (p < e) {
            unsigned short u[16];
            float sc[16];
#pragma unroll
            for (int j = 0; j < 16; ++j) {
                int q = p + j;
                sc[j] = (q < e) ? 1.f : 0.f;
                int r = csr_src[(q < e) ? q : e - 1];
                u[j] = mu[(size_t)r * (C / 2) + lane];
            }
#pragma unroll
            for (int j = 0; j < 16; ++j) {
                float2 f = fp8x2(u[j]);
                a0 = fmaf(sc[j], f.x, a0);
                a1 = fmaf(sc[j], f.y, a1);
            }
        }
        float2 b = *(const float2*)&bias[2 * lane];
        a0 = fmaxf(di * a0 + b.x, 0.f);
        a1 = fmaxf(di * a1 + b.y, 0.f);
        if (PRESCALE) { a0 *= di; a1 *= di; }
        ((unsigned int*)out)[(size_t)i * (C / 2) + lane] = packbf(a0, a1);
    }
}

// ---------------- two-stage mean pool: per-(graph,split) partial sums, few atomics ----------------
// (fusing this into the aggregate via per-node atomics was a 5x regression: 6.4M RMWs
// onto 12.8K hot addresses serialize; this form pre-reduces ~62 nodes/wave -> 102K atomics)

__global__ void pool_partial(const short* __restrict__ h3, const int* __restrict__ batch,
                             float* __restrict__ pooled) {
    int g = blockIdx.x, sp = blockIdx.y;
    int t = threadIdx.x; // 64 threads, 2 channels each (C3=128)
    __shared__ int seg[2];
    if (t < 2) {
        int target = g + t;
        int lo = 0, hi = N_NODES;
        while (lo < hi) { int mid = (lo + hi) >> 1; if (batch[mid] < target) lo = mid + 1; else hi = mid; }
        seg[t] = lo;
    }
    __syncthreads();
    int start = seg[0], end = seg[1];
    int len = end - start;
    int chunk = (len + PSPLIT - 1) / PSPLIT;
    int a = start + sp * chunk;
    int b = a + chunk; if (b > end) b = end;
    if (a >= b) return;
    const unsigned int* hu = (const unsigned int*)h3;
    float s0 = 0.f, s1 = 0.f;
    int i = a;
    for (; i + 4 <= b; i += 4) {
        unsigned int u0 = hu[(size_t)(i + 0) * (C3 / 2) + t];
        unsigned int u1 = hu[(size_t)(i + 1) * (C3 / 2) + t];
        unsigned int u2 = hu[(size_t)(i + 2) * (C3 / 2) + t];
        unsigned int u3 = hu[(size_t)(i + 3) * (C3 / 2) + t];
        s0 += bflo(u0) + bflo(u1) + bflo(u2) + bflo(u3);
        s1 += bfhi(u0) + bfhi(u1) + bfhi(u2) + bfhi(u3);
    }
    for (; i < b; ++i) {
        unsigned int u = hu[(size_t)i * (C3 / 2) + t];
        s0 += bflo(u);
        s1 += bfhi(u);
    }
    atomicAdd(&pooled[g * C3 + 2 * t], s0);
    atomicAdd(&pooled[g * C3 + 2 * t + 1], s1);
}

// ---------------- head: mean-divide + linear + log_softmax ----------------

__global__ void finalize_head(const float* __restrict__ pooled, const int* __restrict__ batch,
                              const float* __restrict__ Wc, const float* __restrict__ bc,
                              float* __restrict__ outp) {
    int g = blockIdx.x;
    int t = threadIdx.x; // 128 threads = C3
    __shared__ int seg[2];
    if (t < 2) {
        int target = g + t;
        int lo = 0, hi = N_NODES;
        while (lo < hi) { int mid = (lo + hi) >> 1; if (batch[mid] < target) lo = mid + 1; else hi = mid; }
        seg[t] = lo;
    }
    __syncthreads();
    float cnt = (float)(seg[1] - seg[0]);
    float pv = pooled[(size_t)g * C3 + t] / fmaxf(cnt, 1.f);
    float p0 = pv * Wc[t * 2 + 0];
    float p1 = pv * Wc[t * 2 + 1];
#pragma unroll
    for (int o = 32; o > 0; o >>= 1) {
        p0 += __shfl_down(p0, o);
        p1 += __shfl_down(p1, o);
    }
    __shared__ float r0[2], r1[2];
    int wid = t >> 6, lane = t & 63;
    if (lane == 0) { r0[wid] = p0; r1[wid] = p1; }
    __syncthreads();
    if (t == 0) {
        float l0 = r0[0] + r0[1] + bc[0];
        float l1 = r1[0] + r1[1] + bc[1];
        float mx = fmaxf(l0, l1);
        float lse = mx + logf(expf(l0 - mx) + expf(l1 - mx));
        outp[g * 2 + 0] = l0 - lse;
        outp[g * 2 + 1] = l1 - lse;
    }
}

// ---------------- launch ----------------

extern "C" void kernel_launch(void* const* d_in, const int* in_sizes, int n_in,
                              void* d_out, int out_size, void* d_ws, size_t ws_size,
                              hipStream_t stream) {
    const float* x = (const float*)d_in[0];
    const float* W1 = (const float*)d_in[1];
    const float* b1 = (const float*)d_in[2];
    const float* W2 = (const float*)d_in[3];
    const float* b2 = (const float*)d_in[4];
    const float* W3 = (const float*)d_in[5];
    const float* b3 = (const float*)d_in[6];
    const float* Wc = (const float*)d_in[7];
    const float* bc = (const float*)d_in[8];
    const int* ei = (const int*)d_in[9];
    const int* batch = (const int*)d_in[10];
    const int* row = ei;
    const int* col = ei + N_EDGES;
    float* out = (float*)d_out;

    char* ws = (char*)d_ws;
    size_t off = 0;
    auto alloc = [&](size_t bytes) -> void* {
        off = (off + 255) & ~(size_t)255;
        void* p = ws + off;
        off += bytes;
        return p;
    };

    // zero-init region first: one memset covers counts + pooled
    int* counts = (int*)alloc((size_t)N_NODES * 4);
    float* pooled = (float*)alloc((size_t)NGRAPH * C3 * 4);
    size_t zero_bytes = off;

    int* offsets = (int*)alloc((size_t)(N_NODES + 1) * 4);
    int* cursor = (int*)alloc((size_t)N_NODES * 4);
    int* chunksums = (int*)alloc(256 * 4);
    float* dis = (float*)alloc((size_t)N_NODES * 4);
    float4* xd = (float4*)alloc((size_t)N_NODES * 16);
    int* csr_src = (int*)alloc((size_t)N_EDGES * 4);
    short* W2t = (short*)alloc((size_t)C1 * C2 * 2);   // [C2][C1] bf16
    short* W3t = (short*)alloc((size_t)C2 * C3 * 2);   // [C3][C2] bf16
    unsigned char* m2 = (unsigned char*)alloc((size_t)N_NODES * C2); // fp8
    short* h2 = (short*)alloc((size_t)N_NODES * C2 * 2);             // bf16
    unsigned char* m3 = (unsigned char*)alloc((size_t)N_NODES * C3); // fp8
    short* h3 = (short*)alloc((size_t)N_NODES * C3 * 2);             // bf16

    hipMemsetAsync(ws, 0, zero_bytes, stream);

    count_prep<<<NEBLK + WBLK, 256, 0, stream>>>(col, counts, W2, W3, W2t, W3t);
    int nchunks = (N_NODES + 255) / 256;
    scan_chunks<<<nchunks, 256, 0, stream>>>(counts, x, offsets, chunksums, dis, xd);
    finalize_offsets<<<nchunks, 256, 0, stream>>>(offsets, chunksums, cursor);
    scatter_edges<<<NEBLK, 256, 0, stream>>>(row, col, cursor, csr_src);

    gemm_l1<<<(N_NODES + 127) / 128, 512, 0, stream>>>(xd, offsets, csr_src, W1, b1, W2t, m2, N_NODES);
    aggregate_w<C2, true><<<(N_NODES + 3) / 4, 256, 0, stream>>>(m2, offsets, csr_src, dis, b2, h2);

    gemm_bf16<C2, C3><<<(N_NODES + 127) / 128, 512, 0, stream>>>(h2, W3t, m3, N_NODES);
    aggregate_w<C3, false><<<(N_NODES + 3) / 4, 256, 0, stream>>>(m3, offsets, csr_src, dis, b3, h3);

    dim3 gp(NGRAPH, PSPLIT);
    pool_partial<<<gp, C3 / 2, 0, stream>>>(h3, batch, pooled);
    finalize_head<<<NGRAPH, C3, 0, stream>>>(pooled, batch, Wc, bc, out);
}

// Round 9
// 279.062 us; speedup vs baseline: 1.0410x; 1.0410x over previous
//
#include <hip/hip_runtime.h>
#include <hip/hip_bf16.h>
#include <hip/hip_fp8.h>
#include <math.h>

#define N_NODES 50000
#define N_EDGES 800000
#define NFEAT 3
#define C1 512
#define C2 256
#define C3 128
#define NGRAPH 100
#define NCLS 2
#define PSPLIT 8
#define NRANGE 8
#define RANGE_SZ 6250    // N_NODES / NRANGE
#define NE4 200000       // N_EDGES / 4 (int4 elements)
#define NRCHUNK 391      // ceil(NE4 / 512) -- 2048 edges per block
#define WBLK 640         // (C1*C2 + C2*C3) / 256

typedef short bh8 __attribute__((ext_vector_type(8)));   // 8 bf16 bit-patterns (4 VGPRs)
typedef float f32x4 __attribute__((ext_vector_type(4))); // MFMA accumulator

__device__ __forceinline__ short f2bf(float x) {
    __hip_bfloat16 h = __float2bfloat16(x);
    return *reinterpret_cast<short*>(&h);
}
__device__ __forceinline__ float bflo(unsigned int u) { return __uint_as_float(u << 16); }
__device__ __forceinline__ float bfhi(unsigned int u) { return __uint_as_float(u & 0xffff0000u); }
__device__ __forceinline__ unsigned int packbf(float a, float b) {
    return (unsigned int)(unsigned short)f2bf(a) | ((unsigned int)(unsigned short)f2bf(b) << 16);
}
// OCP e4m3 fp8 encode; packed-pair decode (HW v_cvt_pk_f32_fp8 on gfx950)
__device__ __forceinline__ unsigned char f2fp8(float x) {
    __hip_fp8_e4m3 q(x);
    return (unsigned char)q.__x;
}
__device__ __forceinline__ float2 fp8x2(unsigned short u) {
    __hip_fp8x2_e4m3 q; q.__x = u; return (float2)q;
}

// async global->LDS, 16B per lane (global_load_lds_dwordx4). LDS dest must be
// wave-uniform base + lane*16 (HW constraint, m104); global src is per-lane.
__device__ __forceinline__ void gload16(const void* g, void* l) {
    __builtin_amdgcn_global_load_lds((const __attribute__((address_space(1))) void*)g,
                                     (__attribute__((address_space(3))) void*)l, 16, 0, 0);
}

// ---- edge kernels: XCD-RANGE-PARTITIONED (the load-bearing design), chunked grid ----
// Measured two-point experiment (r6: 782 blk/int4 = 45.9us @27% occ; r8: 3125 blk/1-edge
// = 50.9us @54% occ): single-pass scatter is ~50us REGARDLESS of TLP. The limiter is
// cursor cache-line ownership migrating between all 8 XCDs' L2s (~256 atomics/line).
// range = blockIdx&7 with the %8 round-robin block->XCD map makes every atomic target
// XCD-local (r1-r5 form: never in top-5). This version keeps that binding but processes
// 2048 edges/block via int4 (avg 1 in-range atomic per thread): 25,000 -> 3,128 blocks.

__global__ void count_prep(const int4* __restrict__ col4, int* __restrict__ counts,
                           const float* __restrict__ W2, const float* __restrict__ W3,
                           short* __restrict__ W2t, short* __restrict__ W3t) {
    int b = blockIdx.x;
    if (b < NRCHUNK * NRANGE) {
        int range = b & (NRANGE - 1);
        int lo = range * RANGE_SZ, hi = lo + RANGE_SZ;
        int base = (b >> 3) * 512 + threadIdx.x;
#pragma unroll
        for (int h = 0; h < 2; ++h) {
            int i = base + h * 256;
            if (i < NE4) {
                int4 c = col4[i];
                if (c.x >= lo && c.x < hi) atomicAdd(&counts[c.x], 1);
                if (c.y >= lo && c.y < hi) atomicAdd(&counts[c.y], 1);
                if (c.z >= lo && c.z < hi) atomicAdd(&counts[c.z], 1);
                if (c.w >= lo && c.w < hi) atomicAdd(&counts[c.w], 1);
            }
        }
    } else {
        int idx = (b - NRCHUNK * NRANGE) * 256 + threadIdx.x;
        if (idx < C1 * C2) {
            int n = idx / C1, k = idx % C1;
            W2t[idx] = f2bf(W2[k * C2 + n]);
        } else if (idx < C1 * C2 + C2 * C3) {
            int j = idx - C1 * C2;
            int n = j / C2, k = j % C2;
            W3t[j] = f2bf(W3[k * C3 + n]);
        }
    }
}

// ------- CSR build: per-chunk scan (fused dis + packed xd={x,dis}) -------

__global__ void scan_chunks(const int* __restrict__ counts, const float* __restrict__ x,
                            int* __restrict__ offsets, int* __restrict__ chunksums,
                            float* __restrict__ dis, float4* __restrict__ xd) {
    __shared__ int s[256];
    int b = blockIdx.x, t = threadIdx.x;
    int i = b * 256 + t;
    int v = (i < N_NODES) ? counts[i] : 0;
    if (i < N_NODES) {
        float d = rsqrtf((float)(v + 1)); // +1 self loop
        dis[i] = d;
        xd[i] = make_float4(x[i * 3 + 0], x[i * 3 + 1], x[i * 3 + 2], d);
    }
    s[t] = v;
    __syncthreads();
    for (int d = 1; d < 256; d <<= 1) {
        int add = (t >= d) ? s[t - d] : 0;
        __syncthreads();
        s[t] += add;
        __syncthreads();
    }
    if (i < N_NODES) offsets[i + 1] = s[t];
    if (t == 255) chunksums[b] = s[255];
}

// finalize offsets: every block redundantly scans the 196 raw chunk sums in LDS,
// then applies its chunk offset. Also initializes cursor[] = final offsets.

__global__ void finalize_offsets(int* __restrict__ offsets, const int* __restrict__ chunksums,
                                 int* __restrict__ cursor) {
    __shared__ int s[256];
    int b = blockIdx.x, t = threadIdx.x;
    int nck = (N_NODES + 255) / 256; // 196
    s[t] = (t < nck) ? chunksums[t] : 0;
    __syncthreads();
    for (int d = 1; d < 256; d <<= 1) {
        int add = (t >= d) ? s[t - d] : 0;
        __syncthreads();
        s[t] += add;
        __syncthreads();
    }
    int add = (b == 0) ? 0 : s[b - 1];
    int i = b * 256 + t;
    if (i < N_NODES) {
        int val = offsets[i + 1] + add;
        offsets[i + 1] = val;
        if (i + 1 < N_NODES) cursor[i + 1] = val;
    }
    if (i == 0) { offsets[0] = 0; cursor[0] = 0; }
}

// XCD-range-partitioned CSR scatter (see count_prep comment). csr_src order within a
// node's list is atomic grab order -- aggregation sums are order-insensitive.

__global__ void scatter_edges(const int4* __restrict__ row4, const int4* __restrict__ col4,
                              int* __restrict__ cursor, int* __restrict__ csr_src) {
    int b = blockIdx.x;
    int range = b & (NRANGE - 1);
    int lo = range * RANGE_SZ, hi = lo + RANGE_SZ;
    int base = (b >> 3) * 512 + threadIdx.x;
#pragma unroll
    for (int h = 0; h < 2; ++h) {
        int i = base + h * 256;
        if (i < NE4) {
            int4 c = col4[i];
            int4 r = row4[i];
            if (c.x >= lo && c.x < hi) { int p = atomicAdd(&cursor[c.x], 1); csr_src[p] = r.x; }
            if (c.y >= lo && c.y < hi) { int p = atomicAdd(&cursor[c.y], 1); csr_src[p] = r.y; }
            if (c.z >= lo && c.z < hi) { int p = atomicAdd(&cursor[c.z], 1); csr_src[p] = r.z; }
            if (c.w >= lo && c.w < hi) { int p = atomicAdd(&cursor[c.w], 1); csr_src[p] = r.w; }
        }
    }
}

// ---- FUSED feat-aggregate + layer1 + GEMM2: m2 = (di*relu(agg(x)@W1+b1)) @ W2t^T, fp8 out ----
// Prologue computes the block's 128 aggx rows in-LDS (16 lanes/node, shuffle-reduced).
// Bs staging uses global_load_lds width=16 (lane-linear LDS dest, per-lane global src).

__global__ __launch_bounds__(512, 4) void gemm_l1(const float4* __restrict__ xd,
                                                  const int* __restrict__ offsets,
                                                  const int* __restrict__ csr_src,
                                                  const float* __restrict__ W1,
                                                  const float* __restrict__ b1,
                                                  const short* __restrict__ Bt,
                                                  unsigned char* __restrict__ Cmat, int M) {
    __shared__ short As[128 * 32];
    __shared__ short Bs[C2 * 32];
    __shared__ float sW1[3 * C1];
    __shared__ float sb1[C1];
    __shared__ float sa[128 * 3];
    __shared__ float sd[128];
    int bm = blockIdx.x * 128;
    int t = threadIdx.x;
    int wave = t >> 6, lane = t & 63, quad = lane >> 4, l16 = lane & 15;
    int wm = (wave >> 2) * 64;
    int wn = (wave & 3) * 64;
    f32x4 acc[4][4] = {};

    for (int j = t; j < 3 * C1; j += 512) sW1[j] = W1[j];
    if (t < C1) sb1[t] = b1[t];

    // prologue: 4 rounds x 32 concurrent nodes (16 lanes each) -> sa, sd
    int lg = t & 15;
#pragma unroll
    for (int rnd = 0; rnd < 4; ++rnd) {
        int rloc = rnd * 32 + (t >> 4);         // 0..127
        int i = bm + rloc; if (i > M - 1) i = M - 1;
        int s0 = offsets[i], e0 = offsets[i + 1];
        float a0 = 0.f, a1 = 0.f, a2 = 0.f;
        for (int p = s0 + lg; p < e0; p += 16) {
            int r = csr_src[p];
            float4 v = xd[r];
            a0 += v.w * v.x;
            a1 += v.w * v.y;
            a2 += v.w * v.z;
        }
#pragma unroll
        for (int m = 1; m < 16; m <<= 1) {
            a0 += __shfl_xor(a0, m);
            a1 += __shfl_xor(a1, m);
            a2 += __shfl_xor(a2, m);
        }
        if (lg == 0) {
            float4 self = xd[i];
            float di = self.w;
            a0 += di * self.x; a1 += di * self.y; a2 += di * self.z;
            sa[rloc * 3 + 0] = di * a0;
            sa[rloc * 3 + 1] = di * a1;
            sa[rloc * 3 + 2] = di * a2;
            sd[rloc] = di;
        }
    }
    __syncthreads();

    int ar = t >> 2, ak = (t & 3) * 8;
    float a0 = sa[ar * 3 + 0], a1 = sa[ar * 3 + 1], a2 = sa[ar * 3 + 2];
    float drow = sd[ar];

    // staging chunk ids for Bs (two per thread): c -> row c>>2, koff (c&3)*8
    int c0 = t, c1 = 512 + t;
    int b0row = c0 >> 2, b0off = (c0 & 3) * 8;
    int b1row = c1 >> 2, b1off = (c1 & 3) * 8;

    for (int k0 = 0; k0 < C1; k0 += 32) {
#pragma unroll
        for (int j = 0; j < 8; ++j) {
            int k = k0 + ak + j;
            float v = a0 * sW1[k] + a1 * sW1[C1 + k] + a2 * sW1[2 * C1 + k] + sb1[k];
            As[ar * 32 + ak + j] = f2bf(drow * fmaxf(v, 0.f));
        }
        gload16(Bt + (size_t)b0row * C1 + k0 + b0off, &Bs[c0 * 8]);
        gload16(Bt + (size_t)b1row * C1 + k0 + b1off, &Bs[c1 * 8]);
        __syncthreads();
        bh8 af[4], bf[4];
#pragma unroll
        for (int mt = 0; mt < 4; ++mt)
            af[mt] = *(const bh8*)&As[(wm + mt * 16 + l16) * 32 + quad * 8];
#pragma unroll
        for (int nt = 0; nt < 4; ++nt)
            bf[nt] = *(const bh8*)&Bs[(wn + nt * 16 + l16) * 32 + quad * 8];
#pragma unroll
        for (int mt = 0; mt < 4; ++mt)
#pragma unroll
            for (int nt = 0; nt < 4; ++nt)
                acc[mt][nt] = __builtin_amdgcn_mfma_f32_16x16x32_bf16(af[mt], bf[nt], acc[mt][nt], 0, 0, 0);
        __syncthreads();
    }

#pragma unroll
    for (int mt = 0; mt < 4; ++mt)
#pragma unroll
        for (int nt = 0; nt < 4; ++nt) {
            int colc = wn + nt * 16 + l16;
#pragma unroll
            for (int r = 0; r < 4; ++r) {
                int rowc = bm + wm + mt * 16 + quad * 4 + r;
                if (rowc < M) Cmat[(size_t)rowc * C2 + colc] = f2fp8(acc[mt][nt][r]);
            }
        }
}

// ------- bf16 MFMA GEMM (K=256, BN=128), OUTPUT FP8: C[M x BN] = A[M x K] * Bt^T -------
// A and B staging via global_load_lds width=16 (lane-linear LDS byte 16t).

template <int K, int BN>
__global__ __launch_bounds__(512, 4) void gemm_bf16(const short* __restrict__ A,
                                                    const short* __restrict__ Bt,
                                                    unsigned char* __restrict__ Cmat, int M) {
    __shared__ short As[128 * 32];
    __shared__ short Bs[BN * 32];
    constexpr int NT = BN / 64;
    int bm = blockIdx.x * 128;
    int t = threadIdx.x;
    int wave = t >> 6, lane = t & 63, quad = lane >> 4, l16 = lane & 15;
    int wm = (wave >> 2) * 64;
    int wn = (wave & 3) * (BN / 4);
    f32x4 acc[4][NT] = {};

    int ar = t >> 2, ak = (t & 3) * 8;
    int agr = bm + ar; if (agr > M - 1) agr = M - 1;
    const short* aptr = A + (size_t)agr * K + ak;
    const short* bptr = Bt + (size_t)(t >> 2) * K + ((t & 3) * 8); // BN==128 layout

    for (int k0 = 0; k0 < K; k0 += 32) {
        gload16(aptr + k0, &As[t * 8]);
        static_assert(BN == 128, "staging specialized for BN==128");
        gload16(bptr + k0, &Bs[t * 8]);
        __syncthreads();
        bh8 af[4], bf[NT];
#pragma unroll
        for (int mt = 0; mt < 4; ++mt)
            af[mt] = *(const bh8*)&As[(wm + mt * 16 + l16) * 32 + quad * 8];
#pragma unroll
        for (int nt = 0; nt < NT; ++nt)
            bf[nt] = *(const bh8*)&Bs[(wn + nt * 16 + l16) * 32 + quad * 8];
#pragma unroll
        for (int mt = 0; mt < 4; ++mt)
#pragma unroll
            for (int nt = 0; nt < NT; ++nt)
                acc[mt][nt] = __builtin_amdgcn_mfma_f32_16x16x32_bf16(af[mt], bf[nt], acc[mt][nt], 0, 0, 0);
        __syncthreads();
    }

#pragma unroll
    for (int mt = 0; mt < 4; ++mt)
#pragma unroll
        for (int nt = 0; nt < NT; ++nt) {
            int colc = wn + nt * 16 + l16;
#pragma unroll
            for (int r = 0; r < 4; ++r) {
                int rowc = bm + wm + mt * 16 + quad * 4 + r;
                if (rowc < M) Cmat[(size_t)rowc * BN + colc] = f2fp8(acc[mt][nt][r]);
            }
        }
}

// ---- fp8-message aggregation, wave-per-node, 16-deep masked gather batches ----

template <int C, bool PRESCALE>
__global__ __launch_bounds__(256) void aggregate_w(const unsigned char* __restrict__ m,
                                                   const int* __restrict__ offsets,
                                                   const int* __restrict__ csr_src,
                                                   const float* __restrict__ dis,
                                                   const float* __restrict__ bias,
                                                   short* __restrict__ out) {
    int i = blockIdx.x * 4 + (threadIdx.x >> 6);
    if (i >= N_NODES) return;
    int lane = threadIdx.x & 63;
    int s = __builtin_amdgcn_readfirstlane(offsets[i]);
    int e = __builtin_amdgcn_readfirstlane(offsets[i + 1]);
    float di = __uint_as_float(__builtin_amdgcn_readfirstlane(__float_as_uint(dis[i])));

    if constexpr (C == 256) {
        // lane owns channels 4*lane .. 4*lane+3 (one uint = 4 fp8)
        const unsigned int* mu = (const unsigned int*)m;
        unsigned int su = mu[(size_t)i * (C / 4) + lane];
        float2 slo = fp8x2((unsigned short)(su & 0xffffu));
        float2 shi = fp8x2((unsigned short)(su >> 16));
        float a0 = slo.x, a1 = slo.y, a2 = shi.x, a3 = shi.y;
        int p = s;
        for (; p + 16 <= e; p += 16) {
            unsigned int u[16];
#pragma unroll
            for (int j = 0; j < 16; ++j) {
                int r = csr_src[p + j];
                u[j] = mu[(size_t)r * (C / 4) + lane];
            }
#pragma unroll
            for (int j = 0; j < 16; ++j) {
                float2 lo = fp8x2((unsigned short)(u[j] & 0xffffu));
                float2 hi = fp8x2((unsigned short)(u[j] >> 16));
                a0 += lo.x; a1 += lo.y; a2 += hi.x; a3 += hi.y;
            }
        }
        if (p < e) {
            unsigned int u[16];
            float sc[16];
#pragma unroll
            for (int j = 0; j < 16; ++j) {
                int q = p + j;
                sc[j] = (q < e) ? 1.f : 0.f;
                int r = csr_src[(q < e) ? q : e - 1];
                u[j] = mu[(size_t)r * (C / 4) + lane];
            }
#pragma unroll
            for (int j = 0; j < 16; ++j) {
                float2 lo = fp8x2((unsigned short)(u[j] & 0xffffu));
                float2 hi = fp8x2((unsigned short)(u[j] >> 16));
                a0 = fmaf(sc[j], lo.x, a0);
                a1 = fmaf(sc[j], lo.y, a1);
                a2 = fmaf(sc[j], hi.x, a2);
                a3 = fmaf(sc[j], hi.y, a3);
            }
        }
        float4 b = *(const float4*)&bias[4 * lane];
        a0 = fmaxf(di * a0 + b.x, 0.f);
        a1 = fmaxf(di * a1 + b.y, 0.f);
        a2 = fmaxf(di * a2 + b.z, 0.f);
        a3 = fmaxf(di * a3 + b.w, 0.f);
        if (PRESCALE) { a0 *= di; a1 *= di; a2 *= di; a3 *= di; }
        uint2 o;
        o.x = packbf(a0, a1);
        o.y = packbf(a2, a3);
        *(uint2*)(out + (size_t)i * C + 4 * lane) = o;
    } else {
        // C == 128: lane owns channels 2*lane, 2*lane+1 (one ushort = 2 fp8)
        const unsigned short* mu = (const unsigned short*)m;
        float2 sf = fp8x2(mu[(size_t)i * (C / 2) + lane]);
        float a0 = sf.x, a1 = sf.y;
        int p = s;
        for (; p + 16 <= e; p += 16) {
            unsigned short u[16];
#pragma unroll
            for (int j = 0; j < 16; ++j) {
                int r = csr_src[p + j];
                u[j] = mu[(size_t)r * (C / 2) + lane];
            }
#pragma unroll
            for (int j = 0; j < 16; ++j) {
                float2 f = fp8x2(u[j]);
                a0 += f.x; a1 += f.y;
            }
        }
        if (p < e) {
            unsigned short u[16];
            float sc[16];
#pragma unroll
            for (int j = 0; j < 16; ++j) {
                int q = p + j;
                sc[j] = (q < e) ? 1.f : 0.f;
                int r = csr_src[(q < e) ? q : e - 1];
                u[j] = mu[(size_t)r * (C / 2) + lane];
            }
#pragma unroll
            for (int j = 0; j < 16; ++j) {
                float2 f = fp8x2(u[j]);
                a0 = fmaf(sc[j], f.x, a0);
                a1 = fmaf(sc[j], f.y, a1);
            }
        }
        float2 b = *(const float2*)&bias[2 * lane];
        a0 = fmaxf(di * a0 + b.x, 0.f);
        a1 = fmaxf(di * a1 + b.y, 0.f);
        if (PRESCALE) { a0 *= di; a1 *= di; }
        ((unsigned int*)out)[(size_t)i * (C / 2) + lane] = packbf(a0, a1);
    }
}

// ---------------- two-stage mean pool: per-(graph,split) partial sums, few atomics ----------------
// (fusing this into the aggregate via per-node atomics was a 5x regression: 6.4M RMWs
// onto 12.8K hot addresses serialize; this form pre-reduces ~62 nodes/wave -> 102K atomics)

__global__ void pool_partial(const short* __restrict__ h3, const int* __restrict__ batch,
                             float* __restrict__ pooled) {
    int g = blockIdx.x, sp = blockIdx.y;
    int t = threadIdx.x; // 64 threads, 2 channels each (C3=128)
    __shared__ int seg[2];
    if (t < 2) {
        int target = g + t;
        int lo = 0, hi = N_NODES;
        while (lo < hi) { int mid = (lo + hi) >> 1; if (batch[mid] < target) lo = mid + 1; else hi = mid; }
        seg[t] = lo;
    }
    __syncthreads();
    int start = seg[0], end = seg[1];
    int len = end - start;
    int chunk = (len + PSPLIT - 1) / PSPLIT;
    int a = start + sp * chunk;
    int b = a + chunk; if (b > end) b = end;
    if (a >= b) return;
    const unsigned int* hu = (const unsigned int*)h3;
    float s0 = 0.f, s1 = 0.f;
    int i = a;
    for (; i + 4 <= b; i += 4) {
        unsigned int u0 = hu[(size_t)(i + 0) * (C3 / 2) + t];
        unsigned int u1 = hu[(size_t)(i + 1) * (C3 / 2) + t];
        unsigned int u2 = hu[(size_t)(i + 2) * (C3 / 2) + t];
        unsigned int u3 = hu[(size_t)(i + 3) * (C3 / 2) + t];
        s0 += bflo(u0) + bflo(u1) + bflo(u2) + bflo(u3);
        s1 += bfhi(u0) + bfhi(u1) + bfhi(u2) + bfhi(u3);
    }
    for (; i < b; ++i) {
        unsigned int u = hu[(size_t)i * (C3 / 2) + t];
        s0 += bflo(u);
        s1 += bfhi(u);
    }
    atomicAdd(&pooled[g * C3 + 2 * t], s0);
    atomicAdd(&pooled[g * C3 + 2 * t + 1], s1);
}

// ---------------- head: mean-divide + linear + log_softmax ----------------

__global__ void finalize_head(const float* __restrict__ pooled, const int* __restrict__ batch,
                              const float* __restrict__ Wc, const float* __restrict__ bc,
                              float* __restrict__ outp) {
    int g = blockIdx.x;
    int t = threadIdx.x; // 128 threads = C3
    __shared__ int seg[2];
    if (t < 2) {
        int target = g + t;
        int lo = 0, hi = N_NODES;
        while (lo < hi) { int mid = (lo + hi) >> 1; if (batch[mid] < target) lo = mid + 1; else hi = mid; }
        seg[t] = lo;
    }
    __syncthreads();
    float cnt = (float)(seg[1] - seg[0]);
    float pv = pooled[(size_t)g * C3 + t] / fmaxf(cnt, 1.f);
    float p0 = pv * Wc[t * 2 + 0];
    float p1 = pv * Wc[t * 2 + 1];
#pragma unroll
    for (int o = 32; o > 0; o >>= 1) {
        p0 += __shfl_down(p0, o);
        p1 += __shfl_down(p1, o);
    }
    __shared__ float r0[2], r1[2];
    int wid = t >> 6, lane = t & 63;
    if (lane == 0) { r0[wid] = p0; r1[wid] = p1; }
    __syncthreads();
    if (t == 0) {
        float l0 = r0[0] + r0[1] + bc[0];
        float l1 = r1[0] + r1[1] + bc[1];
        float mx = fmaxf(l0, l1);
        float lse = mx + logf(expf(l0 - mx) + expf(l1 - mx));
        outp[g * 2 + 0] = l0 - lse;
        outp[g * 2 + 1] = l1 - lse;
    }
}

// ---------------- launch ----------------

extern "C" void kernel_launch(void* const* d_in, const int* in_sizes, int n_in,
                              void* d_out, int out_size, void* d_ws, size_t ws_size,
                              hipStream_t stream) {
    const float* x = (const float*)d_in[0];
    const float* W1 = (const float*)d_in[1];
    const float* b1 = (const float*)d_in[2];
    const float* W2 = (const float*)d_in[3];
    const float* b2 = (const float*)d_in[4];
    const float* W3 = (const float*)d_in[5];
    const float* b3 = (const float*)d_in[6];
    const float* Wc = (const float*)d_in[7];
    const float* bc = (const float*)d_in[8];
    const int* ei = (const int*)d_in[9];
    const int* batch = (const int*)d_in[10];
    const int4* row4 = (const int4*)ei;
    const int4* col4 = (const int4*)(ei + N_EDGES);
    float* out = (float*)d_out;

    char* ws = (char*)d_ws;
    size_t off = 0;
    auto alloc = [&](size_t bytes) -> void* {
        off = (off + 255) & ~(size_t)255;
        void* p = ws + off;
        off += bytes;
        return p;
    };

    // zero-init region first: one memset covers counts + pooled
    int* counts = (int*)alloc((size_t)N_NODES * 4);
    float* pooled = (float*)alloc((size_t)NGRAPH * C3 * 4);
    size_t zero_bytes = off;

    int* offsets = (int*)alloc((size_t)(N_NODES + 1) * 4);
    int* cursor = (int*)alloc((size_t)N_NODES * 4);
    int* chunksums = (int*)alloc(256 * 4);
    float* dis = (float*)alloc((size_t)N_NODES * 4);
    float4* xd = (float4*)alloc((size_t)N_NODES * 16);
    int* csr_src = (int*)alloc((size_t)N_EDGES * 4);
    short* W2t = (short*)alloc((size_t)C1 * C2 * 2);   // [C2][C1] bf16
    short* W3t = (short*)alloc((size_t)C2 * C3 * 2);   // [C3][C2] bf16
    unsigned char* m2 = (unsigned char*)alloc((size_t)N_NODES * C2); // fp8
    short* h2 = (short*)alloc((size_t)N_NODES * C2 * 2);             // bf16
    unsigned char* m3 = (unsigned char*)alloc((size_t)N_NODES * C3); // fp8
    short* h3 = (short*)alloc((size_t)N_NODES * C3 * 2);             // bf16

    hipMemsetAsync(ws, 0, zero_bytes, stream);

    count_prep<<<NRCHUNK * NRANGE + WBLK, 256, 0, stream>>>(col4, counts, W2, W3, W2t, W3t);
    int nchunks = (N_NODES + 255) / 256;
    scan_chunks<<<nchunks, 256, 0, stream>>>(counts, x, offsets, chunksums, dis, xd);
    finalize_offsets<<<nchunks, 256, 0, stream>>>(offsets, chunksums, cursor);
    scatter_edges<<<NRCHUNK * NRANGE, 256, 0, stream>>>(row4, col4, cursor, csr_src);

    gemm_l1<<<(N_NODES + 127) / 128, 512, 0, stream>>>(xd, offsets, csr_src, W1, b1, W2t, m2, N_NODES);
    aggregate_w<C2, true><<<(N_NODES + 3) / 4, 256, 0, stream>>>(m2, offsets, csr_src, dis, b2, h2);

    gemm_bf16<C2, C3><<<(N_NODES + 127) / 128, 512, 0, stream>>>(h2, W3t, m3, N_NODES);
    aggregate_w<C3, false><<<(N_NODES + 3) / 4, 256, 0, stream>>>(m3, offsets, csr_src, dis, b3, h3);

    dim3 gp(NGRAPH, PSPLIT);
    pool_partial<<<gp, C3 / 2, 0, stream>>>(h3, batch, pooled);
    finalize_head<<<NGRAPH, C3, 0, stream>>>(pooled, batch, Wc, bc, out);
}

// Round 10
// 273.948 us; speedup vs baseline: 1.0604x; 1.0187x over previous
//
#include <hip/hip_runtime.h>
#include <hip/hip_bf16.h>
#include <hip/hip_fp8.h>
#include <math.h>

#define N_NODES 50000
#define N_EDGES 800000
#define NFEAT 3
#define C1 512
#define C2 256
#define C3 128
#define NGRAPH 100
#define NCLS 2
#define NRANGE 8
#define RANGE_SZ 6250    // N_NODES / NRANGE
#define NE4 200000       // N_EDGES / 4 (int4 elements)
#define NRCHUNK 391      // ceil(NE4 / 512) -- 2048 edges per block
#define WBLK 640         // (C1*C2 + C2*C3) / 256

typedef short bh8 __attribute__((ext_vector_type(8)));   // 8 bf16 bit-patterns (4 VGPRs)
typedef float f32x4 __attribute__((ext_vector_type(4))); // MFMA accumulator

__device__ __forceinline__ short f2bf(float x) {
    __hip_bfloat16 h = __float2bfloat16(x);
    return *reinterpret_cast<short*>(&h);
}
__device__ __forceinline__ float bflo(unsigned int u) { return __uint_as_float(u << 16); }
__device__ __forceinline__ float bfhi(unsigned int u) { return __uint_as_float(u & 0xffff0000u); }
__device__ __forceinline__ unsigned int packbf(float a, float b) {
    return (unsigned int)(unsigned short)f2bf(a) | ((unsigned int)(unsigned short)f2bf(b) << 16);
}
// OCP e4m3 fp8 encode; packed-pair decode (HW v_cvt_pk_f32_fp8 on gfx950)
__device__ __forceinline__ unsigned char f2fp8(float x) {
    __hip_fp8_e4m3 q(x);
    return (unsigned char)q.__x;
}
__device__ __forceinline__ float2 fp8x2(unsigned short u) {
    __hip_fp8x2_e4m3 q; q.__x = u; return (float2)q;
}

// async global->LDS, 16B per lane (global_load_lds_dwordx4). LDS dest must be
// wave-uniform base + lane*16 (HW constraint, m104); global src is per-lane.
__device__ __forceinline__ void gload16(const void* g, void* l) {
    __builtin_amdgcn_global_load_lds((const __attribute__((address_space(1))) void*)g,
                                     (__attribute__((address_space(3))) void*)l, 16, 0, 0);
}

// ---- edge kernels: XCD-RANGE-PARTITIONED (the load-bearing design), chunked grid ----
// Two-point experiment (r6: 782 blk/int4 = 45.9us @27% occ; r8: 3125 blk/1-edge =
// 50.9us @54% occ): single-pass scatter is ~50us REGARDLESS of TLP -- cursor line
// ownership migrating between 8 XCDs' L2s is the limiter. range = blockIdx&7 with the
// %8 round-robin block->XCD map keeps every atomic XCD-local (r9: out of top-5).

__global__ void count_prep(const int4* __restrict__ col4, int* __restrict__ counts,
                           const float* __restrict__ W2, const float* __restrict__ W3,
                           short* __restrict__ W2t, short* __restrict__ W3t) {
    int b = blockIdx.x;
    if (b < NRCHUNK * NRANGE) {
        int range = b & (NRANGE - 1);
        int lo = range * RANGE_SZ, hi = lo + RANGE_SZ;
        int base = (b >> 3) * 512 + threadIdx.x;
#pragma unroll
        for (int h = 0; h < 2; ++h) {
            int i = base + h * 256;
            if (i < NE4) {
                int4 c = col4[i];
                if (c.x >= lo && c.x < hi) atomicAdd(&counts[c.x], 1);
                if (c.y >= lo && c.y < hi) atomicAdd(&counts[c.y], 1);
                if (c.z >= lo && c.z < hi) atomicAdd(&counts[c.z], 1);
                if (c.w >= lo && c.w < hi) atomicAdd(&counts[c.w], 1);
            }
        }
    } else {
        int idx = (b - NRCHUNK * NRANGE) * 256 + threadIdx.x;
        if (idx < C1 * C2) {
            int n = idx / C1, k = idx % C1;
            W2t[idx] = f2bf(W2[k * C2 + n]);
        } else if (idx < C1 * C2 + C2 * C3) {
            int j = idx - C1 * C2;
            int n = j / C2, k = j % C2;
            W3t[j] = f2bf(W3[k * C3 + n]);
        }
    }
}

// ------- CSR build: per-chunk scan (fused dis + packed xd={x,dis}) -------

__global__ void scan_chunks(const int* __restrict__ counts, const float* __restrict__ x,
                            int* __restrict__ offsets, int* __restrict__ chunksums,
                            float* __restrict__ dis, float4* __restrict__ xd) {
    __shared__ int s[256];
    int b = blockIdx.x, t = threadIdx.x;
    int i = b * 256 + t;
    int v = (i < N_NODES) ? counts[i] : 0;
    if (i < N_NODES) {
        float d = rsqrtf((float)(v + 1)); // +1 self loop
        dis[i] = d;
        xd[i] = make_float4(x[i * 3 + 0], x[i * 3 + 1], x[i * 3 + 2], d);
    }
    s[t] = v;
    __syncthreads();
    for (int d = 1; d < 256; d <<= 1) {
        int add = (t >= d) ? s[t - d] : 0;
        __syncthreads();
        s[t] += add;
        __syncthreads();
    }
    if (i < N_NODES) offsets[i + 1] = s[t];
    if (t == 255) chunksums[b] = s[255];
}

// finalize offsets: every block redundantly scans the 196 raw chunk sums in LDS,
// then applies its chunk offset. Also initializes cursor[] = final offsets.

__global__ void finalize_offsets(int* __restrict__ offsets, const int* __restrict__ chunksums,
                                 int* __restrict__ cursor) {
    __shared__ int s[256];
    int b = blockIdx.x, t = threadIdx.x;
    int nck = (N_NODES + 255) / 256; // 196
    s[t] = (t < nck) ? chunksums[t] : 0;
    __syncthreads();
    for (int d = 1; d < 256; d <<= 1) {
        int add = (t >= d) ? s[t - d] : 0;
        __syncthreads();
        s[t] += add;
        __syncthreads();
    }
    int add = (b == 0) ? 0 : s[b - 1];
    int i = b * 256 + t;
    if (i < N_NODES) {
        int val = offsets[i + 1] + add;
        offsets[i + 1] = val;
        if (i + 1 < N_NODES) cursor[i + 1] = val;
    }
    if (i == 0) { offsets[0] = 0; cursor[0] = 0; }
}

// XCD-range-partitioned CSR scatter (see count_prep comment). csr_src order within a
// node's list is atomic grab order -- aggregation sums are order-insensitive.

__global__ void scatter_edges(const int4* __restrict__ row4, const int4* __restrict__ col4,
                              int* __restrict__ cursor, int* __restrict__ csr_src) {
    int b = blockIdx.x;
    int range = b & (NRANGE - 1);
    int lo = range * RANGE_SZ, hi = lo + RANGE_SZ;
    int base = (b >> 3) * 512 + threadIdx.x;
#pragma unroll
    for (int h = 0; h < 2; ++h) {
        int i = base + h * 256;
        if (i < NE4) {
            int4 c = col4[i];
            int4 r = row4[i];
            if (c.x >= lo && c.x < hi) { int p = atomicAdd(&cursor[c.x], 1); csr_src[p] = r.x; }
            if (c.y >= lo && c.y < hi) { int p = atomicAdd(&cursor[c.y], 1); csr_src[p] = r.y; }
            if (c.z >= lo && c.z < hi) { int p = atomicAdd(&cursor[c.z], 1); csr_src[p] = r.z; }
            if (c.w >= lo && c.w < hi) { int p = atomicAdd(&cursor[c.w], 1); csr_src[p] = r.w; }
        }
    }
}

// ---- FUSED feat-aggregate + layer1 + GEMM2: m2 = (di*relu(agg(x)@W1+b1)) @ W2t^T, fp8 out ----
// Prologue computes the block's 128 aggx rows in-LDS (16 lanes/node, shuffle-reduced).
// Bs staging uses global_load_lds width=16 (lane-linear LDS dest, per-lane global src).

__global__ __launch_bounds__(512, 4) void gemm_l1(const float4* __restrict__ xd,
                                                  const int* __restrict__ offsets,
                                                  const int* __restrict__ csr_src,
                                                  const float* __restrict__ W1,
                                                  const float* __restrict__ b1,
                                                  const short* __restrict__ Bt,
                                                  unsigned char* __restrict__ Cmat, int M) {
    __shared__ short As[128 * 32];
    __shared__ short Bs[C2 * 32];
    __shared__ float sW1[3 * C1];
    __shared__ float sb1[C1];
    __shared__ float sa[128 * 3];
    __shared__ float sd[128];
    int bm = blockIdx.x * 128;
    int t = threadIdx.x;
    int wave = t >> 6, lane = t & 63, quad = lane >> 4, l16 = lane & 15;
    int wm = (wave >> 2) * 64;
    int wn = (wave & 3) * 64;
    f32x4 acc[4][4] = {};

    for (int j = t; j < 3 * C1; j += 512) sW1[j] = W1[j];
    if (t < C1) sb1[t] = b1[t];

    // prologue: 4 rounds x 32 concurrent nodes (16 lanes each) -> sa, sd
    int lg = t & 15;
#pragma unroll
    for (int rnd = 0; rnd < 4; ++rnd) {
        int rloc = rnd * 32 + (t >> 4);         // 0..127
        int i = bm + rloc; if (i > M - 1) i = M - 1;
        int s0 = offsets[i], e0 = offsets[i + 1];
        float a0 = 0.f, a1 = 0.f, a2 = 0.f;
        for (int p = s0 + lg; p < e0; p += 16) {
            int r = csr_src[p];
            float4 v = xd[r];
            a0 += v.w * v.x;
            a1 += v.w * v.y;
            a2 += v.w * v.z;
        }
#pragma unroll
        for (int m = 1; m < 16; m <<= 1) {
            a0 += __shfl_xor(a0, m);
            a1 += __shfl_xor(a1, m);
            a2 += __shfl_xor(a2, m);
        }
        if (lg == 0) {
            float4 self = xd[i];
            float di = self.w;
            a0 += di * self.x; a1 += di * self.y; a2 += di * self.z;
            sa[rloc * 3 + 0] = di * a0;
            sa[rloc * 3 + 1] = di * a1;
            sa[rloc * 3 + 2] = di * a2;
            sd[rloc] = di;
        }
    }
    __syncthreads();

    int ar = t >> 2, ak = (t & 3) * 8;
    float a0 = sa[ar * 3 + 0], a1 = sa[ar * 3 + 1], a2 = sa[ar * 3 + 2];
    float drow = sd[ar];

    // staging chunk ids for Bs (two per thread): c -> row c>>2, koff (c&3)*8
    int c0 = t, c1 = 512 + t;
    int b0row = c0 >> 2, b0off = (c0 & 3) * 8;
    int b1row = c1 >> 2, b1off = (c1 & 3) * 8;

    for (int k0 = 0; k0 < C1; k0 += 32) {
#pragma unroll
        for (int j = 0; j < 8; ++j) {
            int k = k0 + ak + j;
            float v = a0 * sW1[k] + a1 * sW1[C1 + k] + a2 * sW1[2 * C1 + k] + sb1[k];
            As[ar * 32 + ak + j] = f2bf(drow * fmaxf(v, 0.f));
        }
        gload16(Bt + (size_t)b0row * C1 + k0 + b0off, &Bs[c0 * 8]);
        gload16(Bt + (size_t)b1row * C1 + k0 + b1off, &Bs[c1 * 8]);
        __syncthreads();
        bh8 af[4], bf[4];
#pragma unroll
        for (int mt = 0; mt < 4; ++mt)
            af[mt] = *(const bh8*)&As[(wm + mt * 16 + l16) * 32 + quad * 8];
#pragma unroll
        for (int nt = 0; nt < 4; ++nt)
            bf[nt] = *(const bh8*)&Bs[(wn + nt * 16 + l16) * 32 + quad * 8];
#pragma unroll
        for (int mt = 0; mt < 4; ++mt)
#pragma unroll
            for (int nt = 0; nt < 4; ++nt)
                acc[mt][nt] = __builtin_amdgcn_mfma_f32_16x16x32_bf16(af[mt], bf[nt], acc[mt][nt], 0, 0, 0);
        __syncthreads();
    }

#pragma unroll
    for (int mt = 0; mt < 4; ++mt)
#pragma unroll
        for (int nt = 0; nt < 4; ++nt) {
            int colc = wn + nt * 16 + l16;
#pragma unroll
            for (int r = 0; r < 4; ++r) {
                int rowc = bm + wm + mt * 16 + quad * 4 + r;
                if (rowc < M) Cmat[(size_t)rowc * C2 + colc] = f2fp8(acc[mt][nt][r]);
            }
        }
}

// ------- bf16 MFMA GEMM (K=256, BN=128), OUTPUT FP8: C[M x BN] = A[M x K] * Bt^T -------
// A and B staging via global_load_lds width=16 (lane-linear LDS byte 16t).

template <int K, int BN>
__global__ __launch_bounds__(512, 4) void gemm_bf16(const short* __restrict__ A,
                                                    const short* __restrict__ Bt,
                                                    unsigned char* __restrict__ Cmat, int M) {
    __shared__ short As[128 * 32];
    __shared__ short Bs[BN * 32];
    constexpr int NT = BN / 64;
    int bm = blockIdx.x * 128;
    int t = threadIdx.x;
    int wave = t >> 6, lane = t & 63, quad = lane >> 4, l16 = lane & 15;
    int wm = (wave >> 2) * 64;
    int wn = (wave & 3) * (BN / 4);
    f32x4 acc[4][NT] = {};

    int ar = t >> 2, ak = (t & 3) * 8;
    int agr = bm + ar; if (agr > M - 1) agr = M - 1;
    const short* aptr = A + (size_t)agr * K + ak;
    const short* bptr = Bt + (size_t)(t >> 2) * K + ((t & 3) * 8); // BN==128 layout

    for (int k0 = 0; k0 < K; k0 += 32) {
        gload16(aptr + k0, &As[t * 8]);
        static_assert(BN == 128, "staging specialized for BN==128");
        gload16(bptr + k0, &Bs[t * 8]);
        __syncthreads();
        bh8 af[4], bf[NT];
#pragma unroll
        for (int mt = 0; mt < 4; ++mt)
            af[mt] = *(const bh8*)&As[(wm + mt * 16 + l16) * 32 + quad * 8];
#pragma unroll
        for (int nt = 0; nt < NT; ++nt)
            bf[nt] = *(const bh8*)&Bs[(wn + nt * 16 + l16) * 32 + quad * 8];
#pragma unroll
        for (int mt = 0; mt < 4; ++mt)
#pragma unroll
            for (int nt = 0; nt < NT; ++nt)
                acc[mt][nt] = __builtin_amdgcn_mfma_f32_16x16x32_bf16(af[mt], bf[nt], acc[mt][nt], 0, 0, 0);
        __syncthreads();
    }

#pragma unroll
    for (int mt = 0; mt < 4; ++mt)
#pragma unroll
        for (int nt = 0; nt < NT; ++nt) {
            int colc = wn + nt * 16 + l16;
#pragma unroll
            for (int r = 0; r < 4; ++r) {
                int rowc = bm + wm + mt * 16 + quad * 4 + r;
                if (rowc < M) Cmat[(size_t)rowc * BN + colc] = f2fp8(acc[mt][nt][r]);
            }
        }
}

// ---- fp8-message aggregation, wave-per-node, 16-deep masked gather batches ----

template <int C, bool PRESCALE>
__global__ __launch_bounds__(256) void aggregate_w(const unsigned char* __restrict__ m,
                                                   const int* __restrict__ offsets,
                                                   const int* __restrict__ csr_src,
                                                   const float* __restrict__ dis,
                                                   const float* __restrict__ bias,
                                                   short* __restrict__ out) {
    int i = blockIdx.x * 4 + (threadIdx.x >> 6);
    if (i >= N_NODES) return;
    int lane = threadIdx.x & 63;
    int s = __builtin_amdgcn_readfirstlane(offsets[i]);
    int e = __builtin_amdgcn_readfirstlane(offsets[i + 1]);
    float di = __uint_as_float(__builtin_amdgcn_readfirstlane(__float_as_uint(dis[i])));

    if constexpr (C == 256) {
        // lane owns channels 4*lane .. 4*lane+3 (one uint = 4 fp8)
        const unsigned int* mu = (const unsigned int*)m;
        unsigned int su = mu[(size_t)i * (C / 4) + lane];
        float2 slo = fp8x2((unsigned short)(su & 0xffffu));
        float2 shi = fp8x2((unsigned short)(su >> 16));
        float a0 = slo.x, a1 = slo.y, a2 = shi.x, a3 = shi.y;
        int p = s;
        for (; p + 16 <= e; p += 16) {
            unsigned int u[16];
#pragma unroll
            for (int j = 0; j < 16; ++j) {
                int r = csr_src[p + j];
                u[j] = mu[(size_t)r * (C / 4) + lane];
            }
#pragma unroll
            for (int j = 0; j < 16; ++j) {
                float2 lo = fp8x2((unsigned short)(u[j] & 0xffffu));
                float2 hi = fp8x2((unsigned short)(u[j] >> 16));
                a0 += lo.x; a1 += lo.y; a2 += hi.x; a3 += hi.y;
            }
        }
        if (p < e) {
            unsigned int u[16];
            float sc[16];
#pragma unroll
            for (int j = 0; j < 16; ++j) {
                int q = p + j;
                sc[j] = (q < e) ? 1.f : 0.f;
                int r = csr_src[(q < e) ? q : e - 1];
                u[j] = mu[(size_t)r * (C / 4) + lane];
            }
#pragma unroll
            for (int j = 0; j < 16; ++j) {
                float2 lo = fp8x2((unsigned short)(u[j] & 0xffffu));
                float2 hi = fp8x2((unsigned short)(u[j] >> 16));
                a0 = fmaf(sc[j], lo.x, a0);
                a1 = fmaf(sc[j], lo.y, a1);
                a2 = fmaf(sc[j], hi.x, a2);
                a3 = fmaf(sc[j], hi.y, a3);
            }
        }
        float4 b = *(const float4*)&bias[4 * lane];
        a0 = fmaxf(di * a0 + b.x, 0.f);
        a1 = fmaxf(di * a1 + b.y, 0.f);
        a2 = fmaxf(di * a2 + b.z, 0.f);
        a3 = fmaxf(di * a3 + b.w, 0.f);
        if (PRESCALE) { a0 *= di; a1 *= di; a2 *= di; a3 *= di; }
        uint2 o;
        o.x = packbf(a0, a1);
        o.y = packbf(a2, a3);
        *(uint2*)(out + (size_t)i * C + 4 * lane) = o;
    } else {
        // C == 128: lane owns channels 2*lane, 2*lane+1 (one ushort = 2 fp8)
        const unsigned short* mu = (const unsigned short*)m;
        float2 sf = fp8x2(mu[(size_t)i * (C / 2) + lane]);
        float a0 = sf.x, a1 = sf.y;
        int p = s;
        for (; p + 16 <= e; p += 16) {
            unsigned short u[16];
#pragma unroll
            for (int j = 0; j < 16; ++j) {
                int r = csr_src[p + j];
                u[j] = mu[(size_t)r * (C / 2) + lane];
            }
#pragma unroll
            for (int j = 0; j < 16; ++j) {
                float2 f = fp8x2(u[j]);
                a0 += f.x; a1 += f.y;
            }
        }
        if (p < e) {
            unsigned short u[16];
            float sc[16];
#pragma unroll
            for (int j = 0; j < 16; ++j) {
                int q = p + j;
                sc[j] = (q < e) ? 1.f : 0.f;
                int r = csr_src[(q < e) ? q : e - 1];
                u[j] = mu[(size_t)r * (C / 2) + lane];
            }
#pragma unroll
            for (int j = 0; j < 16; ++j) {
                float2 f = fp8x2(u[j]);
                a0 = fmaf(sc[j], f.x, a0);
                a1 = fmaf(sc[j], f.y, a1);
            }
        }
        float2 b = *(const float2*)&bias[2 * lane];
        a0 = fmaxf(di * a0 + b.x, 0.f);
        a1 = fmaxf(di * a1 + b.y, 0.f);
        if (PRESCALE) { a0 *= di; a1 *= di; }
        ((unsigned int*)out)[(size_t)i * (C / 2) + lane] = packbf(a0, a1);
    }
}

// ---- FUSED mean-pool + head: one block per graph, zero atomics, no pooled buffer ----
// 8 waves stride the graph's node range (batch is sorted -> contiguous), fp32 channel
// sums in registers, LDS-combine 8 partials, then linear + log_softmax in-block.
// (round-3 lesson: per-node atomics onto pooled serialize at ~500 RMW/address; this
// form has NO atomics at all.)

__global__ __launch_bounds__(512) void pool_head(const short* __restrict__ h3,
                                                 const int* __restrict__ batch,
                                                 const float* __restrict__ Wc,
                                                 const float* __restrict__ bc,
                                                 float* __restrict__ outp) {
    __shared__ int seg[2];
    __shared__ float part[8][C3];   // 4 KB
    __shared__ float r0[2], r1[2];
    int g = blockIdx.x;
    int t = threadIdx.x;
    int w = t >> 6, lane = t & 63;
    if (t < 2) {
        int target = g + t;
        int lo = 0, hi = N_NODES;
        while (lo < hi) { int mid = (lo + hi) >> 1; if (batch[mid] < target) lo = mid + 1; else hi = mid; }
        seg[t] = lo;
    }
    __syncthreads();
    int start = seg[0], end = seg[1];
    const unsigned int* hu = (const unsigned int*)h3;
    float s0 = 0.f, s1 = 0.f;
    int i = start + w;
    for (; i + 24 < end; i += 32) {
        unsigned int u0 = hu[(size_t)(i + 0)  * (C3 / 2) + lane];
        unsigned int u1 = hu[(size_t)(i + 8)  * (C3 / 2) + lane];
        unsigned int u2 = hu[(size_t)(i + 16) * (C3 / 2) + lane];
        unsigned int u3 = hu[(size_t)(i + 24) * (C3 / 2) + lane];
        s0 += bflo(u0) + bflo(u1) + bflo(u2) + bflo(u3);
        s1 += bfhi(u0) + bfhi(u1) + bfhi(u2) + bfhi(u3);
    }
    for (; i < end; i += 8) {
        unsigned int u = hu[(size_t)i * (C3 / 2) + lane];
        s0 += bflo(u);
        s1 += bfhi(u);
    }
    part[w][2 * lane] = s0;
    part[w][2 * lane + 1] = s1;
    __syncthreads();
    if (t < C3) {
        float v = 0.f;
#pragma unroll
        for (int j = 0; j < 8; ++j) v += part[j][t];
        float cnt = fmaxf((float)(end - start), 1.f);
        float pv = v / cnt;
        float p0 = pv * Wc[t * 2 + 0];
        float p1 = pv * Wc[t * 2 + 1];
#pragma unroll
        for (int o = 32; o > 0; o >>= 1) {
            p0 += __shfl_down(p0, o);
            p1 += __shfl_down(p1, o);
        }
        if (lane == 0) { r0[w] = p0; r1[w] = p1; }
    }
    __syncthreads();
    if (t == 0) {
        float l0 = r0[0] + r0[1] + bc[0];
        float l1 = r1[0] + r1[1] + bc[1];
        float mx = fmaxf(l0, l1);
        float lse = mx + logf(expf(l0 - mx) + expf(l1 - mx));
        outp[g * 2 + 0] = l0 - lse;
        outp[g * 2 + 1] = l1 - lse;
    }
}

// ---------------- launch ----------------

extern "C" void kernel_launch(void* const* d_in, const int* in_sizes, int n_in,
                              void* d_out, int out_size, void* d_ws, size_t ws_size,
                              hipStream_t stream) {
    const float* x = (const float*)d_in[0];
    const float* W1 = (const float*)d_in[1];
    const float* b1 = (const float*)d_in[2];
    const float* W2 = (const float*)d_in[3];
    const float* b2 = (const float*)d_in[4];
    const float* W3 = (const float*)d_in[5];
    const float* b3 = (const float*)d_in[6];
    const float* Wc = (const float*)d_in[7];
    const float* bc = (const float*)d_in[8];
    const int* ei = (const int*)d_in[9];
    const int* batch = (const int*)d_in[10];
    const int4* row4 = (const int4*)ei;
    const int4* col4 = (const int4*)(ei + N_EDGES);
    float* out = (float*)d_out;

    char* ws = (char*)d_ws;
    size_t off = 0;
    auto alloc = [&](size_t bytes) -> void* {
        off = (off + 255) & ~(size_t)255;
        void* p = ws + off;
        off += bytes;
        return p;
    };

    // zero-init region first: one memset covers counts only (pooled buffer eliminated)
    int* counts = (int*)alloc((size_t)N_NODES * 4);
    size_t zero_bytes = off;

    int* offsets = (int*)alloc((size_t)(N_NODES + 1) * 4);
    int* cursor = (int*)alloc((size_t)N_NODES * 4);
    int* chunksums = (int*)alloc(256 * 4);
    float* dis = (float*)alloc((size_t)N_NODES * 4);
    float4* xd = (float4*)alloc((size_t)N_NODES * 16);
    int* csr_src = (int*)alloc((size_t)N_EDGES * 4);
    short* W2t = (short*)alloc((size_t)C1 * C2 * 2);   // [C2][C1] bf16
    short* W3t = (short*)alloc((size_t)C2 * C3 * 2);   // [C3][C2] bf16
    unsigned char* m2 = (unsigned char*)alloc((size_t)N_NODES * C2); // fp8
    short* h2 = (short*)alloc((size_t)N_NODES * C2 * 2);             // bf16
    unsigned char* m3 = (unsigned char*)alloc((size_t)N_NODES * C3); // fp8
    short* h3 = (short*)alloc((size_t)N_NODES * C3 * 2);             // bf16

    hipMemsetAsync(ws, 0, zero_bytes, stream);

    count_prep<<<NRCHUNK * NRANGE + WBLK, 256, 0, stream>>>(col4, counts, W2, W3, W2t, W3t);
    int nchunks = (N_NODES + 255) / 256;
    scan_chunks<<<nchunks, 256, 0, stream>>>(counts, x, offsets, chunksums, dis, xd);
    finalize_offsets<<<nchunks, 256, 0, stream>>>(offsets, chunksums, cursor);
    scatter_edges<<<NRCHUNK * NRANGE, 256, 0, stream>>>(row4, col4, cursor, csr_src);

    gemm_l1<<<(N_NODES + 127) / 128, 512, 0, stream>>>(xd, offsets, csr_src, W1, b1, W2t, m2, N_NODES);
    aggregate_w<C2, true><<<(N_NODES + 3) / 4, 256, 0, stream>>>(m2, offsets, csr_src, dis, b2, h2);

    gemm_bf16<C2, C3><<<(N_NODES + 127) / 128, 512, 0, stream>>>(h2, W3t, m3, N_NODES);
    aggregate_w<C3, false><<<(N_NODES + 3) / 4, 256, 0, stream>>>(m3, offsets, csr_src, dis, b3, h3);

    pool_head<<<NGRAPH, 512, 0, stream>>>(h3, batch, Wc, bc, out);
}